// Round 13
// baseline (207.854 us; speedup 1.0000x reference)
//
#include <hip/hip_runtime.h>
#include <hip/hip_bf16.h>

typedef unsigned short u16;
typedef unsigned int u32;
typedef float f32x4 __attribute__((ext_vector_type(4)));
typedef short bf16x8 __attribute__((ext_vector_type(8)));

// ---- constants (B=2, S=2048, E=1024, H=16, D=64) ----
#define BB 2
#define SS 2048
#define EE 1024
#define HH 16
#define DD 64
// q pre-scale: 1/sqrt(D) * log2(e) — scores land directly in exp2 domain.
#define QSCALE 0.18033688011f

__device__ __forceinline__ float bf2f(u16 u) {
    union { u32 i; float f; } x; x.i = ((u32)u) << 16; return x.f;
}
__device__ __forceinline__ u16 f2bf(float f) {
    union { u32 i; float f; } x; x.f = f;
    return (u16)((x.i + 0x7FFFu + ((x.i >> 16) & 1u)) >> 16);
}
__device__ __forceinline__ u32 pkbf(float a, float b) {
    __hip_bfloat162 h = __float22bfloat162_rn(make_float2(a, b));
    union { __hip_bfloat162 h; u32 u; } c; c.h = h; return c.u;
}

#define MFMA16(a, b, c) __builtin_amdgcn_mfma_f32_16x16x32_bf16((a), (b), (c), 0, 0, 0)

// async global->LDS DMA, 16B per lane; LDS dest = wave-uniform base + lane*16
__device__ __forceinline__ void gld16(const u16* g, u16* l) {
    __builtin_amdgcn_global_load_lds(
        (const __attribute__((address_space(1))) void*)g,
        (__attribute__((address_space(3))) void*)l,
        16, 0, 0);
}

// ============================================================
// fused fp32 -> bf16 convert of x | W_attn | W_proj into contiguous ws
// ============================================================
__global__ __launch_bounds__(256) void convert_all(
    const float* __restrict__ x, const float* __restrict__ wa,
    const float* __restrict__ wp, u16* __restrict__ dst)
{
    const size_t n0 = (size_t)4096 * 1024;
    const size_t n1 = n0 + (size_t)3072 * 1024;
    size_t i = ((size_t)blockIdx.x * 256 + threadIdx.x) * 4;
    const float* s;
    size_t off;
    if (i < n0)      { s = x;  off = 0;  }
    else if (i < n1) { s = wa; off = n0; }
    else             { s = wp; off = n1; }
    float4 v = *(const float4*)(s + (i - off));
    uint2 o;
    o.x = pkbf(v.x, v.y);
    o.y = pkbf(v.z, v.w);
    *(uint2*)(dst + i) = o;
}

// ============================================================
// GEMM1 v3 (r12): qkv = x*W_attn^T + b_attn — 8-wave 128x128 tile.
// q (pre-scaled QSCALE) / k -> [B,H,S,D]; v -> V^T via LDS transpose.
// grid (24, 32), 512 threads.
// ============================================================
__global__ __launch_bounds__(512, 4) void gemm_qkv(
    const u16* __restrict__ A, const u16* __restrict__ B, const float* __restrict__ bias,
    u16* __restrict__ Qo, u16* __restrict__ Ko, u16* __restrict__ Vto)
{
    __shared__ __align__(16) u16 SMEM[16384];      // As[128*64] | Bs[128*64]; T aliases
    u16* As = SMEM;
    u16* Bs = SMEM + 8192;
    const int n0 = blockIdx.x * 128, m0 = blockIdx.y * 128;
    const int tid = threadIdx.x;
    const int wave = tid >> 6, lane = tid & 63;
    const int l16 = lane & 15, quad = lane >> 4;
    const int wm = wave >> 2, wn = wave & 3;       // 2x4 wave grid
    const int ldr = lane >> 3;
    const int csw = ((lane & 7) ^ ldr) * 8;        // swizzled k-chunk (elems)

    f32x4 acc[4][2];
#pragma unroll
    for (int i = 0; i < 4; ++i)
#pragma unroll
        for (int j = 0; j < 2; ++j) acc[i][j] = f32x4{0.f, 0.f, 0.f, 0.f};

    const int aorb = wave >> 2;                    // 0: stage A, 1: stage B
    u16* stgbuf = aorb ? Bs : As;
    const u16* stgsrc = aorb ? B : A;
    const int stgbase = aorb ? n0 : m0;

    for (int k0 = 0; k0 < 1024; k0 += 64) {
        __syncthreads();
#pragma unroll
        for (int t = 0; t < 4; ++t) {
            const int c = (wave & 3) * 4 + t;      // 0..15
            const int row = c * 8 + ldr;
            gld16(stgsrc + (size_t)(stgbase + row) * 1024 + k0 + csw,
                  &stgbuf[c * 512 + lane * 8]);
        }
        __syncthreads();
#pragma unroll
        for (int ks = 0; ks < 2; ++ks) {
            bf16x8 af[4], bf[2];
#pragma unroll
            for (int i = 0; i < 4; ++i)
                af[i] = *(const bf16x8*)&As[(wm * 64 + i * 16 + l16) * 64 +
                                            ((ks * 4 + quad) ^ (l16 & 7)) * 8];
#pragma unroll
            for (int j = 0; j < 2; ++j)
                bf[j] = *(const bf16x8*)&Bs[(wn * 32 + j * 16 + l16) * 64 +
                                            ((ks * 4 + quad) ^ (l16 & 7)) * 8];
#pragma unroll
            for (int i = 0; i < 4; ++i)
#pragma unroll
                for (int j = 0; j < 2; ++j)
                    acc[i][j] = MFMA16(af[i], bf[j], acc[i][j]);
        }
    }

    const int part = blockIdx.x >> 3;              // 0=q,1=k,2=v
    const int hbase = (blockIdx.x & 7) << 1;
    if (part != 2) {
        const int h = hbase + (wn >> 1);           // uniform per wave
#pragma unroll
        for (int j = 0; j < 2; ++j) {
            const int f = n0 + wn * 32 + j * 16 + l16;
            const int d = f & 63;
            const float bj = bias[f];
#pragma unroll
            for (int i = 0; i < 4; ++i) {
#pragma unroll
                for (int r = 0; r < 4; ++r) {
                    const int m = m0 + wm * 64 + i * 16 + quad * 4 + r;
                    const int b = m >> 11, s = m & 2047;
                    const float val = acc[i][j][r] + bj;
                    if (part == 0)
                        Qo[(((size_t)(b * HH + h)) * SS + s) * DD + d] = f2bf(val * QSCALE);
                    else
                        Ko[(((size_t)(b * HH + h)) * SS + s) * DD + d] = f2bf(val);
                }
            }
        }
    } else {
        // V: transpose C-tile through T (aliases SMEM), two m-half passes
        u16* T = SMEM;                             // 128 x 72
#pragma unroll
        for (int wmr = 0; wmr < 2; ++wmr) {
            __syncthreads();
            if (wm == wmr) {
#pragma unroll
                for (int j = 0; j < 2; ++j) {
                    const float bj = bias[n0 + wn * 32 + j * 16 + l16];
#pragma unroll
                    for (int i = 0; i < 4; ++i) {
                        uint2 pw;
                        pw.x = pkbf(acc[i][j][0] + bj, acc[i][j][1] + bj);
                        pw.y = pkbf(acc[i][j][2] + bj, acc[i][j][3] + bj);
                        *(uint2*)&T[(wn * 32 + j * 16 + l16) * 72 + i * 16 + quad * 4] = pw;
                    }
                }
            }
            __syncthreads();
            const int frow = tid >> 2;             // 0..127 (f_local)
            const int qtr = tid & 3;
            const int h = hbase + (frow >> 6);
            const int d = frow & 63;
            const int mg = m0 + wmr * 64;
            const int b = mg >> 11, sbase = mg & 2047;
            u16* dstrow = Vto + (((size_t)(b * HH + h)) * DD + d) * SS + sbase;
#pragma unroll
            for (int l = 0; l < 4; ++l) {
                const int mo = qtr * 16 + l * 4;
                *(uint2*)(dstrow + mo) = *(const uint2*)&T[frow * 72 + mo];
            }
        }
    }
}

// ============================================================
// GEMM2 v3 (r12): out = o*W_proj^T + b_proj (fp32) — 64x128 tile, 8 waves.
// grid (8, 64), 512 threads.
// ============================================================
__global__ __launch_bounds__(512, 4) void gemm_proj(
    const u16* __restrict__ A, const u16* __restrict__ B, const float* __restrict__ bias,
    float* __restrict__ out)
{
    __shared__ __align__(16) u16 SMEM[12288];      // As[64*64] | Bs[128*64]
    u16* As = SMEM;
    u16* Bs = SMEM + 4096;
    const int n0 = blockIdx.x * 128, m0 = blockIdx.y * 64;
    const int tid = threadIdx.x;
    const int wave = tid >> 6, lane = tid & 63;
    const int l16 = lane & 15, quad = lane >> 4;
    const int wm = wave >> 2, wn = wave & 3;       // 2x4 wave grid
    const int ldr = lane >> 3;
    const int csw = ((lane & 7) ^ ldr) * 8;

    f32x4 acc[2][2];
#pragma unroll
    for (int i = 0; i < 2; ++i)
#pragma unroll
        for (int j = 0; j < 2; ++j) acc[i][j] = f32x4{0.f, 0.f, 0.f, 0.f};

    for (int k0 = 0; k0 < 1024; k0 += 64) {
        __syncthreads();
#pragma unroll
        for (int t = 0; t < 3; ++t) {
            const int c = wave * 3 + t;            // 0..23: A chunks 0-7, B 8-23
            if (c < 8) {
                const int row = c * 8 + ldr;
                gld16(A + (size_t)(m0 + row) * 1024 + k0 + csw, &As[c * 512 + lane * 8]);
            } else {
                const int c2 = c - 8;
                const int row = c2 * 8 + ldr;
                gld16(B + (size_t)(n0 + row) * 1024 + k0 + csw, &Bs[c2 * 512 + lane * 8]);
            }
        }
        __syncthreads();
#pragma unroll
        for (int ks = 0; ks < 2; ++ks) {
            bf16x8 af[2], bf[2];
#pragma unroll
            for (int i = 0; i < 2; ++i)
                af[i] = *(const bf16x8*)&As[(wm * 32 + i * 16 + l16) * 64 +
                                            ((ks * 4 + quad) ^ (l16 & 7)) * 8];
#pragma unroll
            for (int j = 0; j < 2; ++j)
                bf[j] = *(const bf16x8*)&Bs[(wn * 32 + j * 16 + l16) * 64 +
                                            ((ks * 4 + quad) ^ (l16 & 7)) * 8];
#pragma unroll
            for (int i = 0; i < 2; ++i)
#pragma unroll
                for (int j = 0; j < 2; ++j)
                    acc[i][j] = MFMA16(af[i], bf[j], acc[i][j]);
        }
    }
#pragma unroll
    for (int j = 0; j < 2; ++j) {
        const int f = n0 + wn * 32 + j * 16 + l16;
        const float bj = bias[f];
#pragma unroll
        for (int i = 0; i < 2; ++i) {
#pragma unroll
            for (int r = 0; r < 4; ++r) {
                const int m = m0 + wm * 32 + i * 16 + quad * 4 + r;
                out[(size_t)m * EE + f] = acc[i][j][r] + bj;
            }
        }
    }
}

// ============================================================
// MFMA flash attention v6, causal — r11 body + 2-way split-K over blocks.
// grid (32, 32, 2): qb = 31-bx, bh = by, half = bz.
// half 0: kb in [0, (qb+1)/2); half 1: [(qb+1)/2, qb+1] (diag in half 1).
// No-max softmax partials are ADDITIVE -> each half writes unnormalized
// O-partial (bf16) + per-row l (fp32) to ws; combine kernel finishes.
// Longest block 17 iters (vs 33); 2048 blocks = 8/CU oversubscribed.
// ============================================================
__global__ __launch_bounds__(256, 4) void attn(
    const u16* __restrict__ Q, const u16* __restrict__ K, const u16* __restrict__ VT,
    u16* __restrict__ OP, float* __restrict__ LP)
{
    const int qb = 31 - (int)blockIdx.x;   // longest first
    const int bh = blockIdx.y;
    const int half = blockIdx.z;
    const int tid = threadIdx.x;
    const int wave = tid >> 6, lane = tid & 63;
    const int l16 = lane & 15, quad = lane >> 4;
    const int ldr = lane >> 3;
    const int csw = ((lane & 7) ^ ldr) * 8;
    __shared__ __align__(16) u16 Ks[64 * 64];
    __shared__ __align__(16) u16 Vts[64 * 64];
    __shared__ __align__(16) u16 Ps[64 * 72];

    const u16* qptr = Q + (size_t)bh * SS * DD;
    const u16* kptr = K + (size_t)bh * SS * DD;
    const u16* vtptr = VT + (size_t)bh * DD * SS;

    const int nh = (qb + 1) >> 1;
    const int klo = half ? nh : 0;
    const int khi = half ? (qb + 1) : nh;

    const int qrow = qb * 64 + wave * 16 + l16;   // this lane's query
    bf16x8 bq[2];
#pragma unroll
    for (int ks = 0; ks < 2; ++ks)
        bq[ks] = *(const bf16x8*)(qptr + (size_t)qrow * DD + ks * 32 + quad * 8);

    float lp = 0.f;                        // per-lane partial l
    f32x4 o_acc[4];
#pragma unroll
    for (int j = 0; j < 4; ++j) o_acc[j] = f32x4{0.f, 0.f, 0.f, 0.f};

    for (int kb = klo; kb < khi; ++kb) {
        const int k0 = kb * 64;
        __syncthreads();
#pragma unroll
        for (int t = 0; t < 2; ++t) {
            const int a0 = wave * 2 + t;
            const int row = a0 * 8 + ldr;
            gld16(kptr + (size_t)(k0 + row) * DD + csw, &Ks[a0 * 512 + lane * 8]);
            gld16(vtptr + (size_t)row * SS + k0 + csw, &Vts[a0 * 512 + lane * 8]);
        }
        __syncthreads();

        // S^T = K·Q^T
        f32x4 s[4];
#pragma unroll
        for (int j = 0; j < 4; ++j) s[j] = f32x4{0.f, 0.f, 0.f, 0.f};
#pragma unroll
        for (int ks = 0; ks < 2; ++ks) {
#pragma unroll
            for (int j = 0; j < 4; ++j) {
                bf16x8 ak = *(const bf16x8*)&Ks[(j * 16 + l16) * 64 +
                                                ((ks * 4 + quad) ^ (l16 & 7)) * 8];
                s[j] = MFMA16(ak, bq[ks], s[j]);
            }
        }

        // ---- no-max softmax: p = exp2(s'), mask only on the diagonal tile ----
        if (kb == qb) {
#pragma unroll
            for (int j = 0; j < 4; ++j)
#pragma unroll
                for (int r = 0; r < 4; ++r) {
                    const int key = k0 + j * 16 + quad * 4 + r;
                    if (key > qrow) s[j][r] = -INFINITY;   // exp2 -> 0
                }
        }
#pragma unroll
        for (int j = 0; j < 4; ++j) {
            const float p0 = __builtin_amdgcn_exp2f(s[j][0]);
            const float p1 = __builtin_amdgcn_exp2f(s[j][1]);
            const float p2 = __builtin_amdgcn_exp2f(s[j][2]);
            const float p3 = __builtin_amdgcn_exp2f(s[j][3]);
            lp += (p0 + p1) + (p2 + p3);
            uint2 pw; pw.x = pkbf(p0, p1); pw.y = pkbf(p2, p3);
            *(uint2*)&Ps[(wave * 16 + l16) * 72 + j * 16 + quad * 4] = pw;
        }

        // O^T += V^T·P^T (Ps wave-private: lgkm ordering suffices)
#pragma unroll
        for (int ks = 0; ks < 2; ++ks) {
            bf16x8 bp = *(const bf16x8*)&Ps[(wave * 16 + l16) * 72 + ks * 32 + quad * 8];
#pragma unroll
            for (int j = 0; j < 4; ++j) {
                bf16x8 av = *(const bf16x8*)&Vts[(j * 16 + l16) * 64 +
                                                 ((ks * 4 + quad) ^ (l16 & 7)) * 8];
                o_acc[j] = MFMA16(av, bp, o_acc[j]);
            }
        }
    }

    // epilogue: write UNNORMALIZED partials (additive across halves)
    const int tile = (half * 32 + bh) * 32 + qb;
    float l = lp;
    l += __shfl_xor(l, 16);
    l += __shfl_xor(l, 32);
    if (quad == 0) LP[tile * 64 + wave * 16 + l16] = l;
    u16* opt = OP + (size_t)tile * 4096;           // [row 0..63][d 0..63]
#pragma unroll
    for (int j = 0; j < 4; ++j) {
        uint2 o4;
        o4.x = pkbf(o_acc[j][0], o_acc[j][1]);
        o4.y = pkbf(o_acc[j][2], o_acc[j][3]);
        *(uint2*)&opt[(wave * 16 + l16) * 64 + j * 16 + quad * 4] = o4;
    }
}

// ============================================================
// combine: ow = (O0 + O1) / (l0 + l1), merged-head layout [B,S,E] bf16.
// grid (32 qtile, 32 bh), 256 threads: thread -> (row = tid>>2, 16 d elems).
// ============================================================
__global__ __launch_bounds__(256) void combine(
    const u16* __restrict__ OP, const float* __restrict__ LP, u16* __restrict__ O)
{
    const int qt = blockIdx.x, bh = blockIdx.y;
    const int row = threadIdx.x >> 2, dg = (threadIdx.x & 3) * 16;
    const int t0 = (0 * 32 + bh) * 32 + qt;
    const int t1 = (1 * 32 + bh) * 32 + qt;
    const u16* p0 = OP + (size_t)t0 * 4096 + row * 64 + dg;
    const u16* p1 = OP + (size_t)t1 * 4096 + row * 64 + dg;
    const float inv = 1.0f / (LP[t0 * 64 + row] + LP[t1 * 64 + row]);
    const int b = bh >> 4, h = bh & 15;
    u16* dst = O + ((size_t)(b * SS + qt * 64 + row)) * EE + h * DD + dg;
    u32 outw[8];
#pragma unroll
    for (int e = 0; e < 8; ++e) {
        const float v0 = (bf2f(p0[2 * e]) + bf2f(p1[2 * e])) * inv;
        const float v1 = (bf2f(p0[2 * e + 1]) + bf2f(p1[2 * e + 1])) * inv;
        outw[e] = pkbf(v0, v1);
    }
#pragma unroll
    for (int e = 0; e < 4; ++e)
        ((uint2*)dst)[e] = make_uint2(outw[2 * e], outw[2 * e + 1]);
}

extern "C" void kernel_launch(void* const* d_in, const int* in_sizes, int n_in,
                              void* d_out, int out_size, void* d_ws, size_t ws_size,
                              hipStream_t stream) {
    const float* x      = (const float*)d_in[0];  // [B,S,E] fp32
    const float* W_attn = (const float*)d_in[1];  // [3E,E] fp32
    const float* b_attn = (const float*)d_in[2];  // [3E] fp32
    const float* W_proj = (const float*)d_in[3];  // [E,E] fp32
    const float* b_proj = (const float*)d_in[4];  // [E] fp32
    float* out = (float*)d_out;                   // fp32 [B,S,E]

    // ws layout (u16 elems): xb 4.19M | wab 3.15M | wpb 1.05M | q 4.19M |
    // k 4.19M | vt 4.19M | op 8.39M | lp 0.26M  (~59 MB total)
    u16* xb  = (u16*)d_ws;
    u16* wab = xb + (size_t)4096 * 1024;
    u16* wpb = wab + (size_t)3072 * 1024;
    u16* qw  = wpb + (size_t)1024 * 1024;
    u16* kw  = qw + (size_t)BB * HH * SS * DD;
    u16* vtw = kw + (size_t)BB * HH * SS * DD;
    u16* op  = vtw + (size_t)BB * HH * SS * DD;    // 2*32*32*4096 bf16 partials
    float* lpb = (float*)(op + (size_t)2 * 32 * 32 * 4096);  // 131072 fp32
    u16* ow  = xb;                                 // xb dead after gemm_qkv

    convert_all<<<8192, 256, 0, stream>>>(x, W_attn, W_proj, xb);
    gemm_qkv<<<dim3(24, 32), 512, 0, stream>>>(xb, wab, b_attn, qw, kw, vtw);
    attn<<<dim3(32, 32, 2), 256, 0, stream>>>(qw, kw, vtw, op, lpb);
    combine<<<dim3(32, 32), 256, 0, stream>>>(op, lpb, ow);
    gemm_proj<<<dim3(8, 64), 512, 0, stream>>>(ow, wpb, b_proj, out);
}